// Round 1
// 996.510 us; speedup vs baseline: 1.1301x; 1.1301x over previous
//
#include <hip/hip_runtime.h>

// Attention_24610162606157 — linear attention block, fp32 end-to-end.
// Pipeline: memset(accums) -> proj (key/query/value @ W + b, + global sums)
//           -> reduce over n (kvs[l,20,20], ks_sum, vs_sum)
//           -> output (attn = (qs·kvs*scale + vs_sum)/(qs·ks_sum*scale + N)) @ Wp + bp
//
// proj v2: no LDS, no barriers. One thread = one token streaming its own
// 1KB row in 8x-float4 batches (MSHR-merges to full 128B lines); k-index is
// wave-uniform so W comes from s_loads (SGPR operand to v_fmac). Grid
// (1024, 3) => 48 waves/CU available vs old LDS-capped 8.

namespace {
constexpr int D    = 256;
constexpr int H    = 20;
constexpr int LDIM = 64;
constexpr int BDIM = 4096;
constexpr int BL   = BDIM * LDIM;   // 262144 tokens
constexpr int TPB  = 256;           // threads per block
constexpr int NSPLIT = 32;          // reduce: splits of the n axis
constexpr int NCHUNK = BDIM / NSPLIT;   // 128 n per reduce block

// workspace layout (float offsets)
constexpr int OFF_KVS  = 0;                         // 64*20*20 = 25600
constexpr int OFF_KSUM = OFF_KVS + LDIM * H * H;    // 25600
constexpr int OFF_VSUM = OFF_KSUM + LDIM * H;       // 26880
constexpr int OFF_SCAL = OFF_VSUM + LDIM * H;       // 28160  [sum_q, sum_k, ss_q, ss_k]
constexpr int ACC_FLOATS = OFF_SCAL + 4;            // 28164 floats to zero
constexpr int OFF_QS   = 28416;                     // aligned start of qs
}

// ---------------------------------------------------------------- projection
// blockIdx.y selects the projection (0=key,1=value,2=query).
__global__ __launch_bounds__(TPB) void proj_kernel(
    const float* __restrict__ key, const float* __restrict__ value,
    const float* __restrict__ query,
    const float* __restrict__ Wk, const float* __restrict__ bk,
    const float* __restrict__ Wq, const float* __restrict__ bq,
    const float* __restrict__ Wv, const float* __restrict__ bv,
    float* __restrict__ qs, float* __restrict__ ks, float* __restrict__ vs,
    float* __restrict__ scalars)
{
    const int tid   = threadIdx.x;
    const int which = blockIdx.y;

    const float* in; const float* W; const float* bias; float* out;
    float* sum_dst = nullptr; float* ss_dst = nullptr;
    if (which == 0)      { in = key;   W = Wk; bias = bk; out = ks;
                           sum_dst = scalars + 1; ss_dst = scalars + 3; }
    else if (which == 1) { in = value; W = Wv; bias = bv; out = vs; }
    else                 { in = query; W = Wq; bias = bq; out = qs;
                           sum_dst = scalars + 0; ss_dst = scalars + 2; }

    const size_t token = (size_t)blockIdx.x * TPB + tid;
    const float4* __restrict__ row =
        reinterpret_cast<const float4*>(in) + token * (D / 4);

    float acc[H];
#pragma unroll
    for (int m = 0; m < H; ++m) acc[m] = 0.f;

    // 8 batches of 8 float4 = one 128B line per lane per batch.
    for (int c = 0; c < 8; ++c) {
        float4 x[8];
#pragma unroll
        for (int u = 0; u < 8; ++u) x[u] = row[c * 8 + u];

        const float* __restrict__ Wc = W + c * 32 * H;   // uniform -> s_load
#pragma unroll
        for (int u = 0; u < 8; ++u) {
            const float xv0 = x[u].x, xv1 = x[u].y, xv2 = x[u].z, xv3 = x[u].w;
            const float* __restrict__ W0 = Wc + (u * 4 + 0) * H;
            const float* __restrict__ W1 = Wc + (u * 4 + 1) * H;
            const float* __restrict__ W2 = Wc + (u * 4 + 2) * H;
            const float* __restrict__ W3 = Wc + (u * 4 + 3) * H;
#pragma unroll
            for (int m = 0; m < H; ++m) {   // k-ascending per acc[m] (matches v1 order)
                acc[m] = fmaf(xv0, W0[m], acc[m]);
                acc[m] = fmaf(xv1, W1[m], acc[m]);
                acc[m] = fmaf(xv2, W2[m], acc[m]);
                acc[m] = fmaf(xv3, W3[m], acc[m]);
            }
        }
    }

    float v[H];
    float s1 = 0.f, s2 = 0.f;
#pragma unroll
    for (int m = 0; m < H; ++m) {
        v[m] = acc[m] + bias[m];
        s1 += v[m];
        s2 = fmaf(v[m], v[m], s2);
    }
    float4* o4 = reinterpret_cast<float4*>(out + token * H);
    o4[0] = make_float4(v[0],  v[1],  v[2],  v[3]);
    o4[1] = make_float4(v[4],  v[5],  v[6],  v[7]);
    o4[2] = make_float4(v[8],  v[9],  v[10], v[11]);
    o4[3] = make_float4(v[12], v[13], v[14], v[15]);
    o4[4] = make_float4(v[16], v[17], v[18], v[19]);

    if (sum_dst) {  // wave reduce then 1 atomic per wave
#pragma unroll
        for (int off = 32; off > 0; off >>= 1) {
            s1 += __shfl_down(s1, off);
            s2 += __shfl_down(s2, off);
        }
        if ((tid & 63) == 0) {
            atomicAdd(sum_dst, s1);
            atomicAdd(ss_dst, s2);
        }
    }
}

// ---------------------------------------------------------------- reduce over n
__global__ __launch_bounds__(TPB) void reduce_kernel(
    const float* __restrict__ ks, const float* __restrict__ vs,
    float* __restrict__ kvs, float* __restrict__ ks_sum, float* __restrict__ vs_sum)
{
    __shared__ float lks[NCHUNK * H];
    __shared__ float lvs[NCHUNK * H];
    const int tid   = threadIdx.x;
    const int l     = blockIdx.x & 63;
    const int split = blockIdx.x >> 6;     // NSPLIT splits of NCHUNK n each
    const int n0    = split * NCHUNK;

    const float4* __restrict__ ks4 = reinterpret_cast<const float4*>(ks);
    const float4* __restrict__ vs4 = reinterpret_cast<const float4*>(vs);
    float4* lks4 = reinterpret_cast<float4*>(lks);
    float4* lvs4 = reinterpret_cast<float4*>(lvs);
    for (int id = tid; id < NCHUNK * (H / 4); id += TPB) {   // 640 float4 each
        int n = id / (H / 4), q = id % (H / 4);
        size_t g = ((size_t)(n0 + n) * LDIM + l) * (H / 4) + q;
        lks4[id] = ks4[g];
        lvs4[id] = vs4[g];
    }
    __syncthreads();

    // kvs slots: thread owns (m,d) = tid and tid+256 (of 400)
    const int s0 = tid, s1 = tid + 256;
    const int m0 = s0 / H, d0 = s0 % H;
    const int m1 = s1 / H, d1 = s1 % H;
    const bool has1 = (s1 < H * H);
    float a0 = 0.f, a1 = 0.f;
    for (int n = 0; n < NCHUNK; ++n) {
        const float* pk = lks + n * H;
        const float* pv = lvs + n * H;
        a0 = fmaf(pk[m0], pv[d0], a0);
        if (has1) a1 = fmaf(pk[m1], pv[d1], a1);
    }
    atomicAdd(&kvs[l * H * H + s0], a0);
    if (has1) atomicAdd(&kvs[l * H * H + s1], a1);

    if (tid < 2 * H) {
        const bool isk = tid < H;
        const int  m   = isk ? tid : tid - H;
        const float* src = isk ? lks : lvs;
        float s = 0.f;
        for (int n = 0; n < NCHUNK; ++n) s += src[n * H + m];
        atomicAdd(isk ? &ks_sum[l * H + m] : &vs_sum[l * H + m], s);
    }
}

// ---------------------------------------------------------------- output
__global__ __launch_bounds__(TPB) void out_kernel(
    const float* __restrict__ qs, const float* __restrict__ kvs,
    const float* __restrict__ ks_sum, const float* __restrict__ vs_sum,
    const float* __restrict__ scalars,
    const float* __restrict__ Wp, const float* __restrict__ bp,
    float* __restrict__ out)
{
    __shared__ float qsl[64 * H];
    __shared__ float attn[64 * H];
    __shared__ float nrm[64];
    const int tid = threadIdx.x;
    const size_t base = (size_t)blockIdx.x * 64;   // one n, tokens l=0..63 (l == t)

    const float sum_q = scalars[0], sum_k = scalars[1];
    const float ss_q  = scalars[2], ss_k  = scalars[3];
    const bool  cond  = (sum_q != 0.f) && (sum_k != 0.f);
    const float scale = cond ? rsqrtf(ss_q) * rsqrtf(ss_k) : 1.f;

    // stage qs for the 64 tokens (fully coalesced: 320 contiguous float4)
    const float4* __restrict__ qs4 = reinterpret_cast<const float4*>(qs) + base * (H / 4);
    float4* qsl4 = reinterpret_cast<float4*>(qsl);
    for (int id = tid; id < 64 * (H / 4); id += TPB) qsl4[id] = qs4[id];
    __syncthreads();

    if (tid < 64) {
        const int t = tid;
        float s = 0.f;
#pragma unroll
        for (int j = 0; j < H; ++j)
            s = fmaf(qsl[t * H + j], ks_sum[t * H + j], s);
        nrm[t] = fmaf(s, scale, (float)BDIM);
    }
    __syncthreads();

    for (int id = tid; id < 64 * H; id += TPB) {
        const int t = id / H, m = id % H;
        float s = 0.f;
#pragma unroll
        for (int j = 0; j < H; ++j)
            s = fmaf(qsl[t * H + j], kvs[t * H * H + j * H + m], s);
        attn[id] = (fmaf(s, scale, vs_sum[t * H + m])) / nrm[t];
    }
    __syncthreads();

    // out[token][tid] = bp[tid] + sum_m attn[t][m] * Wp[m][tid]
    float wp[H];
#pragma unroll
    for (int m = 0; m < H; ++m) wp[m] = Wp[m * D + tid];
    const float bias = bp[tid];
    float* outp = out + base * D + tid;
#pragma unroll 4
    for (int t = 0; t < 64; ++t) {
        const float4* a4 = reinterpret_cast<const float4*>(attn + t * H);
        float acc = bias;
#pragma unroll
        for (int q = 0; q < H / 4; ++q) {
            float4 a = a4[q];   // LDS broadcast (all lanes same addr)
            acc = fmaf(a.x, wp[q * 4 + 0], acc);
            acc = fmaf(a.y, wp[q * 4 + 1], acc);
            acc = fmaf(a.z, wp[q * 4 + 2], acc);
            acc = fmaf(a.w, wp[q * 4 + 3], acc);
        }
        outp[(size_t)t * D] = acc;
    }
}

// ---------------------------------------------------------------- launch
extern "C" void kernel_launch(void* const* d_in, const int* in_sizes, int n_in,
                              void* d_out, int out_size, void* d_ws, size_t ws_size,
                              hipStream_t stream)
{
    const float* key   = (const float*)d_in[0];
    const float* value = (const float*)d_in[1];
    const float* query = (const float*)d_in[2];
    const float* Wk    = (const float*)d_in[3];
    const float* bk    = (const float*)d_in[4];
    const float* Wq    = (const float*)d_in[5];
    const float* bq    = (const float*)d_in[6];
    const float* Wv    = (const float*)d_in[7];
    const float* bv    = (const float*)d_in[8];
    const float* Wp    = (const float*)d_in[9];
    const float* bp    = (const float*)d_in[10];

    float* ws      = (float*)d_ws;
    float* kvs     = ws + OFF_KVS;
    float* ks_sum  = ws + OFF_KSUM;
    float* vs_sum  = ws + OFF_VSUM;
    float* scalars = ws + OFF_SCAL;
    float* qs      = ws + OFF_QS;
    float* ks      = qs + (size_t)BL * H;
    float* vs      = ks + (size_t)BL * H;

    hipMemsetAsync(d_ws, 0, ACC_FLOATS * sizeof(float), stream);

    proj_kernel<<<dim3(BL / TPB, 3), TPB, 0, stream>>>(key, value, query,
                                                       Wk, bk, Wq, bq, Wv, bv,
                                                       qs, ks, vs, scalars);
    reduce_kernel<<<LDIM * NSPLIT, TPB, 0, stream>>>(ks, vs, kvs, ks_sum, vs_sum);
    out_kernel<<<BDIM, TPB, 0, stream>>>(qs, kvs, ks_sum, vs_sum, scalars,
                                         Wp, bp, (float*)d_out);
}